// Round 5
// baseline (23.311 us; speedup 1.0000x reference)
//
#include <hip/hip_runtime.h>

#define DEV __device__ __forceinline__

namespace {

struct CF { float x, y; };

DEV CF cmul(CF a, float c, float s){ return {a.x*c - a.y*s, a.x*s + a.y*c}; }
DEV CF cmulc(CF a, CF b){ return {a.x*b.x - a.y*b.y, a.x*b.y + a.y*b.x}; }
DEV void halfsc(float th, float& c, float& s){ __sincosf(0.5f*th, &s, &c); }

constexpr float RSQRT2 = 0.70710678118654752440f;
constexpr float PI_F   = 3.14159265358979323846f;

// ---- cross-lane xor exchange, all within aligned 32-lane groups -----------
// masks 1,2: DPP quad_perm; 8: DPP row_ror:8; 4,16: ds_swizzle BitMode.
template<int CTRL> DEV float qperm(float v){
  return __int_as_float(__builtin_amdgcn_mov_dpp(__float_as_int(v), CTRL, 0xF, 0xF, true));
}
template<int OFF> DEV float swzf(float v){
  return __int_as_float(__builtin_amdgcn_ds_swizzle(__float_as_int(v), OFF));
}
template<int B> DEV float shfx(float v){
  if constexpr (B==1)      return qperm<0xB1>(v);      // quad_perm [1,0,3,2]
  else if constexpr (B==2) return qperm<0x4E>(v);      // quad_perm [2,3,0,1]
  else if constexpr (B==4) return swzf<0x101F>(v);     // xor 4
  else if constexpr (B==8) return qperm<0x128>(v);     // row_ror:8 == xor 8
  else                     return swzf<0x401F>(v);     // xor 16
}

// ---- fused 1-qubit encoding chain: H; then RZ/RX alternating --------------
template<int NA> DEV void build_psi(CF (&v)[2], const float* ang, float scale){
  v[0] = {RSQRT2, 0.f};
  v[1] = {RSQRT2, 0.f};
  #pragma unroll
  for (int i = 0; i < NA; ++i){
    float c, s; halfsc(scale * ang[i], c, s);
    if ((i & 1) == 0){                     // RZ
      v[0] = cmul(v[0], c, -s);
      v[1] = cmul(v[1], c,  s);
    } else {                               // RX
      CF u0 = v[0], u1 = v[1];
      v[0] = {c*u0.x + s*u1.y, c*u0.y - s*u1.x};
      v[1] = {c*u1.x + s*u0.y, c*u1.y - s*u0.x};
    }
  }
}

// ---- gates on an 8-amp register state -------------------------------------
template<int S> DEV void ry_loc8(CF (&a)[8], float2 cs){
  const float c = cs.x, s = cs.y;
  #pragma unroll
  for (int m = 0; m < 8; ++m) if (!(m & S)) {
    CF u = a[m], v = a[m|S];
    a[m]   = {c*u.x - s*v.x, c*u.y - s*v.y};
    a[m|S] = {s*u.x + c*v.x, s*u.y + c*v.y};
  }
}
template<int MASK> DEV void ry_lane8(CF (&a)[8], int r, float2 cs){
  const float c = cs.x;
  const float sg = (r & MASK) ? cs.y : -cs.y;
  #pragma unroll
  for (int m = 0; m < 8; ++m){
    float ox = shfx<MASK>(a[m].x);
    float oy = shfx<MASK>(a[m].y);
    a[m] = {c*a[m].x + sg*ox, c*a[m].y + sg*oy};
  }
}

DEV CF ld_cf(const float2 v){ return {v.x, v.y}; }

} // namespace

// 8 samples x 32 lanes per 256-thread block; 4096 waves total (4/SIMD)
__global__ __launch_bounds__(256, 4)
void qnn_fused_kernel(const float* __restrict__ X,  const float* __restrict__ w1,
                      const float* __restrict__ w2, const float* __restrict__ fcw,
                      const float* __restrict__ fcb, float* __restrict__ out, int bs)
{
  __shared__ float4 Xlds4[8*49];            // 8 samples x 196 floats, coalesced
  __shared__ float  feats[8][80];           // [64..79] zero pad for chain 7
  __shared__ float4 chain_tab[8][9];        // 8 chains + bank pad
  __shared__ float2 p1phi[32];              // phase-1 merged-CRZ, (l,L,m)
  __shared__ float2 p1ry[8];                // phase-1 RY (c,s) half-angle
  __shared__ float2 ryw[24];                // phase-2 RY (c,s) half-angle
  __shared__ float2 phi2[3*32*9];           // phase-2 merged-CRZ, row-pad 9

  const int t  = threadIdx.x;
  const int sl = t >> 5;                    // local sample 0..7
  const int r  = t & 31;                    // lane id within sample group
  int sample = blockIdx.x * 8 + sl;
  if (sample >= bs) sample = bs - 1;

  // ---------------- coalesced X staging + weight tables --------------------
  {
    const float4* X4 = (const float4*)X;
    for (int idx = t; idx < 8*49; idx += 256){
      int s_ = idx / 49, e = idx - s_*49;
      int gs = blockIdx.x * 8 + s_;
      if (gs >= bs) gs = bs - 1;
      Xlds4[idx] = X4[(size_t)gs*49 + e];
    }
  }
  if (t < 32){                              // p1phi: l = t>>4, L = (t>>3)&1, m = t&7
    const int l = t >> 4, Lb = (t >> 3) & 1, m = t & 7;
    const float h0 = 0.5f*w1[l*8+0], h1 = 0.5f*w1[l*8+1];
    const float h2 = 0.5f*w1[l*8+2], h3 = 0.5f*w1[l*8+3];
    const bool m4 = m & 4, m2 = m & 2, m1 = m & 1;
    float phi = 0.f;
    phi += Lb ? (m4 ? h0 : -h0) : 0.f;      // CRZ(w0,w1)
    phi += m4 ? (m2 ? h1 : -h1) : 0.f;      // CRZ(w1,w2)
    phi += m2 ? (m1 ? h2 : -h2) : 0.f;      // CRZ(w2,w3)
    phi += m1 ? (Lb ? h3 : -h3) : 0.f;      // CRZ(w3,w0)
    float c, s; __sincosf(phi, &s, &c);
    p1phi[t] = {c, s};
  } else if (t < 40){
    const int j = t - 32, l = j >> 2, i = j & 3;
    float c, s; halfsc(w1[l*8 + 4 + i], c, s); p1ry[j] = {c, s};
  } else if (t < 64){
    const int j = t - 40, l = j >> 3, i = j & 7;
    float c, s; halfsc(w2[l*16 + 8 + i], c, s); ryw[j] = {c, s};
  }
  for (int idx = t; idx < 3*256; idx += 256){
    const int l = idx >> 8, rm = idx & 255, rr = rm >> 3, mm = rm & 7;
    const float* wl = w2 + l*16;
    const float h0 = 0.5f*wl[0], h1 = 0.5f*wl[1], h2 = 0.5f*wl[2], h3 = 0.5f*wl[3];
    const float h4 = 0.5f*wl[4], h5 = 0.5f*wl[5], h6 = 0.5f*wl[6], h7 = 0.5f*wl[7];
    const bool b16 = rr & 16, b8 = rr & 8, b4 = rr & 4, b2 = rr & 2, b1 = rr & 1;
    const bool m4 = mm & 4, m2 = mm & 2, m1 = mm & 1;
    float phi = 0.f;
    phi += b16 ? (b8 ? h0 : -h0) : 0.f;     // (w0,w1)
    phi += b8  ? (b4 ? h1 : -h1) : 0.f;     // (w1,w2)
    phi += b4  ? (b2 ? h2 : -h2) : 0.f;     // (w2,w3)
    phi += b2  ? (b1 ? h3 : -h3) : 0.f;     // (w3,w4)
    phi += b1  ? (m4 ? h4 : -h4) : 0.f;     // (w4,w5)
    phi += m4  ? (m2 ? h5 : -h5) : 0.f;     // (w5,w6)
    phi += m2  ? (m1 ? h6 : -h6) : 0.f;     // (w6,w7)
    phi += m1  ? (b16 ? h7 : -h7) : 0.f;    // (w7,w0)
    float c, s; __sincosf(phi, &s, &c);
    phi2[(l*32 + rr)*9 + mm] = {c, s};
  }
  __syncthreads();

  // ---------------- phase 1: patch p = r>>1, wire0 = lane bit r&1 ----------
  {
    const int p  = r >> 1, Lb = r & 1;
    const int pi = p >> 2, pj = p & 3;
    const int i0 = pi*4, j0 = pj*4;
    const int shift = (pj == 3) ? 1 : 2;
    const int cmask = (1 << shift) - 1;
    const int limit = ((pi == 3) ? 2 : 4) << shift;
    const float* Xf = (const float*)Xlds4 + sl*196;
    float px[16];
    #pragma unroll
    for (int k = 0; k < 16; ++k){
      int row = i0 + (k >> shift), col = j0 + (k & cmask);
      int idx = row*14 + col; idx = idx > 195 ? 195 : idx;
      float v = Xf[idx];
      px[k] = (k < limit) ? v : 0.f;        // RZ(0)/RX(0) == identity
    }

    CF ps[4][2];
    #pragma unroll
    for (int q = 0; q < 4; ++q) build_psi<4>(ps[q], &px[q*4], 1.0f);

    // amps: m bits = wires 1,2,3 ; wire0 component selected by lane bit
    CF a8[8];
    {
      CF t12[4];
      #pragma unroll
      for (int j = 0; j < 4; ++j) t12[j] = cmulc(ps[1][j>>1], ps[2][j&1]);
      CF base = Lb ? ps[0][1] : ps[0][0];
      CF bt[4];
      #pragma unroll
      for (int j = 0; j < 4; ++j) bt[j] = cmulc(base, t12[j]);
      #pragma unroll
      for (int m = 0; m < 8; ++m) a8[m] = cmulc(bt[m>>1], ps[3][m&1]);
    }

    #pragma unroll
    for (int l = 0; l < 2; ++l){
      const float2* ph = &p1phi[l*16 + Lb*8];
      #pragma unroll
      for (int m = 0; m < 8; ++m){ float2 cs = ph[m]; a8[m] = cmul(a8[m], cs.x, cs.y); }
      ry_lane8<1>(a8, r, p1ry[l*4+0]);      // wire0 (lane)
      ry_loc8<4>(a8, p1ry[l*4+1]);          // wire1
      ry_loc8<2>(a8, p1ry[l*4+2]);          // wire2
      ry_loc8<1>(a8, p1ry[l*4+3]);          // wire3
    }

    float pr8[8];
    #pragma unroll
    for (int m = 0; m < 8; ++m) pr8[m] = a8[m].x*a8[m].x + a8[m].y*a8[m].y;
    float s_loc = 0.f;
    #pragma unroll
    for (int m = 0; m < 8; ++m) s_loc += pr8[m];
    float e1 = 0.f, e2 = 0.f, e3 = 0.f;
    #pragma unroll
    for (int m = 0; m < 8; ++m){
      e1 += (m & 4) ? -pr8[m] : pr8[m];
      e2 += (m & 2) ? -pr8[m] : pr8[m];
      e3 += (m & 1) ? -pr8[m] : pr8[m];
    }
    float v0 = Lb ? -s_loc : s_loc;
    v0 += shfx<1>(v0); e1 += shfx<1>(e1); e2 += shfx<1>(e2); e3 += shfx<1>(e3);
    // each lane writes 2 features (no divergence)
    feats[sl][p*4 + 2*Lb + 0] = Lb ? e2 : v0;
    feats[sl][p*4 + 2*Lb + 1] = Lb ? e3 : e1;
    if (r < 16) feats[sl][64 + r] = 0.f;    // zero pad f[64..79]
  }
  __syncthreads();

  // ---------------- phase 2 chains: lane r builds chain r&7 ----------------
  {
    const float* f = feats[sl];
    CF v[2];
    const int c = r & 7;
    build_psi<9>(v, f + c*9, PI_F);
    if (r < 8) chain_tab[sl][c] = {v[0].x, v[0].y, v[1].x, v[1].y};
  }
  __syncthreads();

  // ------- assemble product state: lanes = wires 0-4, local = wires 5-7 ----
  CF a[8];
  {
    const float2* c2 = (const float2*)&chain_tab[sl][0];
    CF e0 = ld_cf(c2[0*2 + ((r>>4)&1)]);
    CF e1 = ld_cf(c2[1*2 + ((r>>3)&1)]);
    CF e2 = ld_cf(c2[2*2 + ((r>>2)&1)]);
    CF e3 = ld_cf(c2[3*2 + ((r>>1)&1)]);
    CF e4 = ld_cf(c2[4*2 + ( r    &1)]);
    CF L  = cmulc(cmulc(cmulc(e0, e1), cmulc(e2, e3)), e4);

    float4 q5 = chain_tab[sl][5], q6 = chain_tab[sl][6], q7 = chain_tab[sl][7];
    CF p5[2] = {{q5.x,q5.y},{q5.z,q5.w}};
    CF p6[2] = {{q6.x,q6.y},{q6.z,q6.w}};
    CF p7[2] = {{q7.x,q7.y},{q7.z,q7.w}};
    CF p56[4];
    #pragma unroll
    for (int j = 0; j < 4; ++j) p56[j] = cmulc(p5[j>>1], p6[j&1]);
    CF Lp[4];
    #pragma unroll
    for (int j = 0; j < 4; ++j) Lp[j] = cmulc(L, p56[j]);
    #pragma unroll
    for (int m = 0; m < 8; ++m) a[m] = cmulc(Lp[m>>1], p7[m&1]);
  }

  // ---------------- 3 layers: table-CRZ ring + RY on wires 0..7 ------------
  #pragma unroll
  for (int l = 0; l < 3; ++l){
    const float2* ph = &phi2[(l*32 + r)*9];
    #pragma unroll
    for (int m = 0; m < 8; ++m){ float2 cs = ph[m]; a[m] = cmul(a[m], cs.x, cs.y); }
    ry_lane8<16>(a, r, ryw[l*8+0]);         // wire0
    ry_lane8<8>(a, r, ryw[l*8+1]);          // wire1
    ry_lane8<4>(a, r, ryw[l*8+2]);          // wire2
    ry_lane8<2>(a, r, ryw[l*8+3]);          // wire3
    ry_lane8<1>(a, r, ryw[l*8+4]);          // wire4
    ry_loc8<4>(a, ryw[l*8+5]);              // wire5
    ry_loc8<2>(a, ryw[l*8+6]);              // wire6
    ry_loc8<1>(a, ryw[l*8+7]);              // wire7
  }

  // ---------------- measurement + FC ---------------------------------------
  float pr8[8];
  #pragma unroll
  for (int m = 0; m < 8; ++m) pr8[m] = a[m].x*a[m].x + a[m].y*a[m].y;
  float s_loc = 0.f;
  #pragma unroll
  for (int m = 0; m < 8; ++m) s_loc += pr8[m];
  float e5 = 0.f, e6 = 0.f, e7 = 0.f;
  #pragma unroll
  for (int m = 0; m < 8; ++m){
    e5 += (m & 4) ? -pr8[m] : pr8[m];
    e6 += (m & 2) ? -pr8[m] : pr8[m];
    e7 += (m & 1) ? -pr8[m] : pr8[m];
  }
  float gp[8];
  gp[0] = (r & 16) ? -s_loc : s_loc;
  gp[1] = (r &  8) ? -s_loc : s_loc;
  gp[2] = (r &  4) ? -s_loc : s_loc;
  gp[3] = (r &  2) ? -s_loc : s_loc;
  gp[4] = (r &  1) ? -s_loc : s_loc;
  gp[5] = e5; gp[6] = e6; gp[7] = e7;

  float o0 = 0.f, o1 = 0.f, o2 = 0.f;
  #pragma unroll
  for (int w = 0; w < 8; ++w){
    o0 += fcw[0*8 + w] * gp[w];
    o1 += fcw[1*8 + w] * gp[w];
    o2 += fcw[2*8 + w] * gp[w];
  }
  o0 += shfx<1>(o0);  o1 += shfx<1>(o1);  o2 += shfx<1>(o2);
  o0 += shfx<2>(o0);  o1 += shfx<2>(o1);  o2 += shfx<2>(o2);
  o0 += shfx<4>(o0);  o1 += shfx<4>(o1);  o2 += shfx<4>(o2);
  o0 += shfx<8>(o0);  o1 += shfx<8>(o1);  o2 += shfx<8>(o2);
  o0 += shfx<16>(o0); o1 += shfx<16>(o1); o2 += shfx<16>(o2);

  if (r < 3){
    float o = (r == 0) ? o0 : ((r == 1) ? o1 : o2);
    out[(size_t)sample*3 + r] = o + fcb[r];
  }
}

extern "C" void kernel_launch(void* const* d_in, const int* in_sizes, int n_in,
                              void* d_out, int out_size, void* d_ws, size_t ws_size,
                              hipStream_t stream)
{
  const float* X   = (const float*)d_in[0];
  const float* w1  = (const float*)d_in[1];
  const float* w2  = (const float*)d_in[2];
  const float* fcw = (const float*)d_in[3];
  const float* fcb = (const float*)d_in[4];
  float* out = (float*)d_out;
  const int bs = in_sizes[0] / 196;            // 8192
  const int blocks = (bs + 7) / 8;             // 8 samples / 256-thread block
  hipLaunchKernelGGL(qnn_fused_kernel, dim3(blocks), dim3(256), 0, stream,
                     X, w1, w2, fcw, fcb, out, bs);
}

// Round 6
// 18.194 us; speedup vs baseline: 1.2812x; 1.2812x over previous
//
#include <hip/hip_runtime.h>

#define DEV __device__ __forceinline__

namespace {

typedef float f32x2 __attribute__((ext_vector_type(2)));

DEV f32x2 splat(float x){ f32x2 r; r.x = x; r.y = x; return r; }
DEV f32x2 csw(f32x2 a){ return __builtin_shufflevector(a, a, 1, 0); }
// complex a*b  = (ax bx - ay by, ax by + ay bx)
DEV f32x2 cmulv(f32x2 a, f32x2 b){
  f32x2 nt; nt.x = -b.y; nt.y = b.x;
  return splat(a.x)*b + splat(a.y)*nt;
}
// a * e^{i phi} with cv=(c,c), sv=(-s,s)
DEV f32x2 cphase(f32x2 a, f32x2 cv, f32x2 sv){ return cv*a + sv*csw(a); }
DEV void halfsc(float th, float& c, float& s){ __sincosf(0.5f*th, &s, &c); }

constexpr float RSQRT2 = 0.70710678118654752440f;
constexpr float PI_F   = 3.14159265358979323846f;

// ---- cross-lane xor exchange, all within aligned 32-lane groups -----------
template<int CTRL> DEV float qperm(float v){
  return __int_as_float(__builtin_amdgcn_mov_dpp(__float_as_int(v), CTRL, 0xF, 0xF, true));
}
template<int OFF> DEV float swzf(float v){
  return __int_as_float(__builtin_amdgcn_ds_swizzle(__float_as_int(v), OFF));
}
template<int B> DEV float shfx(float v){
  if constexpr (B==1)      return qperm<0xB1>(v);      // quad_perm [1,0,3,2]
  else if constexpr (B==2) return qperm<0x4E>(v);      // quad_perm [2,3,0,1]
  else if constexpr (B==4) return swzf<0x101F>(v);     // xor 4
  else if constexpr (B==8) return qperm<0x128>(v);     // row_ror:8 == xor 8
  else                     return swzf<0x401F>(v);     // xor 16
}

// ---- fused 1-qubit encoding chain: H; then RZ/RX alternating (packed) -----
template<int NA> DEV void build_psi(f32x2 (&v)[2], const float* ang, float scale){
  v[0].x = RSQRT2; v[0].y = 0.f;
  v[1].x = RSQRT2; v[1].y = 0.f;
  #pragma unroll
  for (int i = 0; i < NA; ++i){
    float c, s; halfsc(scale * ang[i], c, s);
    f32x2 cv = splat(c);
    f32x2 sp; sp.x = s;  sp.y = -s;
    if ((i & 1) == 0){                     // RZ
      f32x2 sn; sn.x = -s; sn.y = s;
      v[0] = cv*v[0] + sp*csw(v[0]);
      v[1] = cv*v[1] + sn*csw(v[1]);
    } else {                               // RX
      f32x2 t0 = csw(v[0]), t1 = csw(v[1]);
      v[0] = cv*v[0] + sp*t1;
      v[1] = cv*v[1] + sp*t0;
    }
  }
}

// ---- gates on an 8-amp register state (packed) ----------------------------
template<int S> DEV void ry_loc8(f32x2 (&a)[8], float2 cs){
  const float c = cs.x, s = cs.y;
  #pragma unroll
  for (int m = 0; m < 8; ++m) if (!(m & S)) {
    f32x2 u = a[m], v = a[m|S];
    a[m]   = splat(c)*u - splat(s)*v;
    a[m|S] = splat(s)*u + splat(c)*v;
  }
}
template<int MASK> DEV void ry_lane8(f32x2 (&a)[8], int r, float2 cs){
  const float c = cs.x;
  const float sg = (r & MASK) ? cs.y : -cs.y;
  #pragma unroll
  for (int m = 0; m < 8; ++m){
    f32x2 o; o.x = shfx<MASK>(a[m].x); o.y = shfx<MASK>(a[m].y);
    a[m] = splat(c)*a[m] + splat(sg)*o;
  }
}

DEV f32x2 tov(float2 v){ f32x2 r; r.x = v.x; r.y = v.y; return r; }

} // namespace

// 8 samples x 32 lanes per 256-thread block
__global__ __launch_bounds__(256, 4)
void qnn_fused_kernel(const float* __restrict__ X,  const float* __restrict__ w1,
                      const float* __restrict__ w2, const float* __restrict__ fcw,
                      const float* __restrict__ fcb, float* __restrict__ out, int bs)
{
  __shared__ float4 Xlds4[8*49];            // 8 samples x 196 floats
  __shared__ float  feats[8][80];           // [64..79] zero pad for chain 7
  __shared__ float4 p1chain[8][16][5];      // phase-1 chains, row pad 5
  __shared__ float4 chain2[8][9];           // phase-2 chains, pad 9
  __shared__ float4 p1phi[2][2][8];         // {c,c,-s,s} per (l,Lb,m)
  __shared__ float2 p1ry[2][4];             // phase-1 RY (c,s) half-angle
  __shared__ float2 ryw[3][8];              // phase-2 RY (c,s) half-angle
  __shared__ float4 phi2[3*32*9];           // {c,c,-s,s}, row pad 9

  const int t  = threadIdx.x;
  const int sl = t >> 5;                    // local sample 0..7
  const int r  = t & 31;                    // lane id within sample group
  int sample = blockIdx.x * 8 + sl;
  if (sample >= bs) sample = bs - 1;

  // ---------------- stage X + weight tables --------------------------------
  {
    const float4* X4 = (const float4*)X;
    for (int idx = t; idx < 8*49; idx += 256){
      int s_ = idx / 49, e = idx - s_*49;
      int gs = blockIdx.x * 8 + s_;
      if (gs >= bs) gs = bs - 1;
      Xlds4[idx] = X4[(size_t)gs*49 + e];
    }
  }
  if (t < 32){                              // p1phi: l=t>>4, Lb=(t>>3)&1, m=t&7
    const int l = t >> 4, Lb = (t >> 3) & 1, m = t & 7;
    const float h0 = 0.5f*w1[l*8+0], h1 = 0.5f*w1[l*8+1];
    const float h2 = 0.5f*w1[l*8+2], h3 = 0.5f*w1[l*8+3];
    const bool m4 = m & 4, m2 = m & 2, m1 = m & 1;
    float phi = 0.f;
    phi += Lb ? (m4 ? h0 : -h0) : 0.f;      // CRZ(w0,w1)
    phi += m4 ? (m2 ? h1 : -h1) : 0.f;      // CRZ(w1,w2)
    phi += m2 ? (m1 ? h2 : -h2) : 0.f;      // CRZ(w2,w3)
    phi += m1 ? (Lb ? h3 : -h3) : 0.f;      // CRZ(w3,w0)
    float c, s; __sincosf(phi, &s, &c);
    p1phi[l][Lb][m] = {c, c, -s, s};
  } else if (t < 40){
    const int j = t - 32, l = j >> 2, i = j & 3;
    float c, s; halfsc(w1[l*8 + 4 + i], c, s); p1ry[l][i] = {c, s};
  } else if (t < 64){
    const int j = t - 40, l = j >> 3, i = j & 7;
    float c, s; halfsc(w2[l*16 + 8 + i], c, s); ryw[l][i] = {c, s};
  }
  for (int idx = t; idx < 3*256; idx += 256){
    const int l = idx >> 8, rr = (idx >> 3) & 31, mm = idx & 7;
    const float* wl = w2 + l*16;
    const float h0 = 0.5f*wl[0], h1 = 0.5f*wl[1], h2 = 0.5f*wl[2], h3 = 0.5f*wl[3];
    const float h4 = 0.5f*wl[4], h5 = 0.5f*wl[5], h6 = 0.5f*wl[6], h7 = 0.5f*wl[7];
    const bool b16 = rr & 16, b8 = rr & 8, b4 = rr & 4, b2 = rr & 2, b1 = rr & 1;
    const bool m4 = mm & 4, m2 = mm & 2, m1 = mm & 1;
    float phi = 0.f;
    phi += b16 ? (b8 ? h0 : -h0) : 0.f;     // (w0,w1)
    phi += b8  ? (b4 ? h1 : -h1) : 0.f;     // (w1,w2)
    phi += b4  ? (b2 ? h2 : -h2) : 0.f;     // (w2,w3)
    phi += b2  ? (b1 ? h3 : -h3) : 0.f;     // (w3,w4)
    phi += b1  ? (m4 ? h4 : -h4) : 0.f;     // (w4,w5)
    phi += m4  ? (m2 ? h5 : -h5) : 0.f;     // (w5,w6)
    phi += m2  ? (m1 ? h6 : -h6) : 0.f;     // (w6,w7)
    phi += m1  ? (b16 ? h7 : -h7) : 0.f;    // (w7,w0)
    float c, s; __sincosf(phi, &s, &c);
    phi2[(l*32 + rr)*9 + mm] = {c, c, -s, s};
  }
  __syncthreads();

  // --------- phase-1 chains: 512 jobs (sample,patch,wire), 2 per thread ----
  #pragma unroll
  for (int jj = 0; jj < 2; ++jj){
    const int j = t + jj*256;
    const int s_ = j >> 6, p = (j >> 2) & 15, q = j & 3;
    const int pi = p >> 2, pj = p & 3;
    const int shift = (pj == 3) ? 1 : 2;
    const int cmask = (1 << shift) - 1;
    const int limit = ((pi == 3) ? 2 : 4) << shift;
    const float* Xf = (const float*)Xlds4 + s_*196;
    float ang[4];
    #pragma unroll
    for (int i = 0; i < 4; ++i){
      const int k = q*4 + i;
      int idx = (pi*4 + (k >> shift))*14 + pj*4 + (k & cmask);
      idx = idx > 195 ? 195 : idx;
      float v = Xf[idx];
      ang[i] = (k < limit) ? v : 0.f;       // RZ(0)/RX(0) == identity
    }
    f32x2 v[2];
    build_psi<4>(v, ang, 1.0f);
    p1chain[s_][p][q] = {v[0].x, v[0].y, v[1].x, v[1].y};
  }
  __syncthreads();

  // ---------------- phase 1 evolution: patch p=r>>1, wire0 = lane bit ------
  {
    const int p = r >> 1, Lb = r & 1;
    f32x2 ps[4][2];
    #pragma unroll
    for (int q = 0; q < 4; ++q){
      float4 f = p1chain[sl][p][q];
      ps[q][0].x = f.x; ps[q][0].y = f.y;
      ps[q][1].x = f.z; ps[q][1].y = f.w;
    }
    f32x2 a8[8];
    {
      f32x2 t12[4];
      #pragma unroll
      for (int j = 0; j < 4; ++j) t12[j] = cmulv(ps[1][j>>1], ps[2][j&1]);
      f32x2 base = Lb ? ps[0][1] : ps[0][0];
      f32x2 bt[4];
      #pragma unroll
      for (int j = 0; j < 4; ++j) bt[j] = cmulv(base, t12[j]);
      #pragma unroll
      for (int m = 0; m < 8; ++m) a8[m] = cmulv(bt[m>>1], ps[3][m&1]);
    }

    #pragma unroll
    for (int l = 0; l < 2; ++l){
      const float4* ph = &p1phi[l][Lb][0];
      #pragma unroll
      for (int m = 0; m < 8; ++m){
        float4 w = ph[m];
        f32x2 cv; cv.x = w.x; cv.y = w.y;
        f32x2 sv; sv.x = w.z; sv.y = w.w;
        a8[m] = cphase(a8[m], cv, sv);
      }
      ry_lane8<1>(a8, r, p1ry[l][0]);       // wire0 (lane)
      ry_loc8<4>(a8, p1ry[l][1]);           // wire1
      ry_loc8<2>(a8, p1ry[l][2]);           // wire2
      ry_loc8<1>(a8, p1ry[l][3]);           // wire3
    }

    float pr8[8];
    #pragma unroll
    for (int m = 0; m < 8; ++m) pr8[m] = a8[m].x*a8[m].x + a8[m].y*a8[m].y;
    float s_loc = 0.f;
    #pragma unroll
    for (int m = 0; m < 8; ++m) s_loc += pr8[m];
    float e1 = 0.f, e2 = 0.f, e3 = 0.f;
    #pragma unroll
    for (int m = 0; m < 8; ++m){
      e1 += (m & 4) ? -pr8[m] : pr8[m];
      e2 += (m & 2) ? -pr8[m] : pr8[m];
      e3 += (m & 1) ? -pr8[m] : pr8[m];
    }
    float v0 = Lb ? -s_loc : s_loc;
    v0 += shfx<1>(v0); e1 += shfx<1>(e1); e2 += shfx<1>(e2); e3 += shfx<1>(e3);
    feats[sl][p*4 + 2*Lb + 0] = Lb ? e2 : v0;
    feats[sl][p*4 + 2*Lb + 1] = Lb ? e3 : e1;
    if (r < 16) feats[sl][64 + r] = 0.f;    // zero pad f[64..79]
  }
  __syncthreads();

  // -------- phase-2 chains: 64 distinct jobs on waves 0-1 only -------------
  if (t < 64){
    const int s_ = t >> 3, c = t & 7;
    f32x2 v[2];
    build_psi<9>(v, &feats[s_][c*9], PI_F);
    chain2[s_][c] = {v[0].x, v[0].y, v[1].x, v[1].y};
  }
  __syncthreads();

  // ------- assemble product state: lanes = wires 0-4, local = wires 5-7 ----
  f32x2 a[8];
  {
    const float2* c2 = (const float2*)&chain2[sl][0];
    f32x2 e0 = tov(c2[0*2 + ((r>>4)&1)]);
    f32x2 e1 = tov(c2[1*2 + ((r>>3)&1)]);
    f32x2 e2 = tov(c2[2*2 + ((r>>2)&1)]);
    f32x2 e3 = tov(c2[3*2 + ((r>>1)&1)]);
    f32x2 e4 = tov(c2[4*2 + ( r    &1)]);
    f32x2 L  = cmulv(cmulv(cmulv(e0, e1), cmulv(e2, e3)), e4);

    float4 q5 = chain2[sl][5], q6 = chain2[sl][6], q7 = chain2[sl][7];
    f32x2 p5[2], p6[2], p7[2];
    p5[0].x=q5.x; p5[0].y=q5.y; p5[1].x=q5.z; p5[1].y=q5.w;
    p6[0].x=q6.x; p6[0].y=q6.y; p6[1].x=q6.z; p6[1].y=q6.w;
    p7[0].x=q7.x; p7[0].y=q7.y; p7[1].x=q7.z; p7[1].y=q7.w;
    f32x2 p56[4];
    #pragma unroll
    for (int j = 0; j < 4; ++j) p56[j] = cmulv(p5[j>>1], p6[j&1]);
    f32x2 Lp[4];
    #pragma unroll
    for (int j = 0; j < 4; ++j) Lp[j] = cmulv(L, p56[j]);
    #pragma unroll
    for (int m = 0; m < 8; ++m) a[m] = cmulv(Lp[m>>1], p7[m&1]);
  }

  // ---------------- 3 layers: table-CRZ ring + RY on wires 0..7 ------------
  #pragma unroll
  for (int l = 0; l < 3; ++l){
    const float4* ph = &phi2[(l*32 + r)*9];
    #pragma unroll
    for (int m = 0; m < 8; ++m){
      float4 w = ph[m];
      f32x2 cv; cv.x = w.x; cv.y = w.y;
      f32x2 sv; sv.x = w.z; sv.y = w.w;
      a[m] = cphase(a[m], cv, sv);
    }
    ry_lane8<16>(a, r, ryw[l][0]);          // wire0
    ry_lane8<8>(a, r, ryw[l][1]);           // wire1
    ry_lane8<4>(a, r, ryw[l][2]);           // wire2
    ry_lane8<2>(a, r, ryw[l][3]);           // wire3
    ry_lane8<1>(a, r, ryw[l][4]);           // wire4
    ry_loc8<4>(a, ryw[l][5]);               // wire5
    ry_loc8<2>(a, ryw[l][6]);               // wire6
    ry_loc8<1>(a, ryw[l][7]);               // wire7
  }

  // ---------------- measurement + FC ---------------------------------------
  float pr8[8];
  #pragma unroll
  for (int m = 0; m < 8; ++m) pr8[m] = a[m].x*a[m].x + a[m].y*a[m].y;
  float s_loc = 0.f;
  #pragma unroll
  for (int m = 0; m < 8; ++m) s_loc += pr8[m];
  float e5 = 0.f, e6 = 0.f, e7 = 0.f;
  #pragma unroll
  for (int m = 0; m < 8; ++m){
    e5 += (m & 4) ? -pr8[m] : pr8[m];
    e6 += (m & 2) ? -pr8[m] : pr8[m];
    e7 += (m & 1) ? -pr8[m] : pr8[m];
  }
  float gp[8];
  gp[0] = (r & 16) ? -s_loc : s_loc;
  gp[1] = (r &  8) ? -s_loc : s_loc;
  gp[2] = (r &  4) ? -s_loc : s_loc;
  gp[3] = (r &  2) ? -s_loc : s_loc;
  gp[4] = (r &  1) ? -s_loc : s_loc;
  gp[5] = e5; gp[6] = e6; gp[7] = e7;

  float o0 = 0.f, o1 = 0.f, o2 = 0.f;
  #pragma unroll
  for (int w = 0; w < 8; ++w){
    o0 += fcw[0*8 + w] * gp[w];
    o1 += fcw[1*8 + w] * gp[w];
    o2 += fcw[2*8 + w] * gp[w];
  }
  o0 += shfx<1>(o0);  o1 += shfx<1>(o1);  o2 += shfx<1>(o2);
  o0 += shfx<2>(o0);  o1 += shfx<2>(o1);  o2 += shfx<2>(o2);
  o0 += shfx<4>(o0);  o1 += shfx<4>(o1);  o2 += shfx<4>(o2);
  o0 += shfx<8>(o0);  o1 += shfx<8>(o1);  o2 += shfx<8>(o2);
  o0 += shfx<16>(o0); o1 += shfx<16>(o1); o2 += shfx<16>(o2);

  if (r < 3){
    float o = (r == 0) ? o0 : ((r == 1) ? o1 : o2);
    out[(size_t)sample*3 + r] = o + fcb[r];
  }
}

extern "C" void kernel_launch(void* const* d_in, const int* in_sizes, int n_in,
                              void* d_out, int out_size, void* d_ws, size_t ws_size,
                              hipStream_t stream)
{
  const float* X   = (const float*)d_in[0];
  const float* w1  = (const float*)d_in[1];
  const float* w2  = (const float*)d_in[2];
  const float* fcw = (const float*)d_in[3];
  const float* fcb = (const float*)d_in[4];
  float* out = (float*)d_out;
  const int bs = in_sizes[0] / 196;            // 8192
  const int blocks = (bs + 7) / 8;             // 8 samples / 256-thread block
  hipLaunchKernelGGL(qnn_fused_kernel, dim3(blocks), dim3(256), 0, stream,
                     X, w1, w2, fcw, fcb, out, bs);
}